// Round 5
// baseline (383.337 us; speedup 1.0000x reference)
//
#include <hip/hip_runtime.h>
#include <hip/hip_bf16.h>

#define N_TOK 4096
#define D_MODEL 1024
#define D_FF 2048
#define N_EXP 8

typedef __attribute__((ext_vector_type(8))) short short8;
typedef __attribute__((ext_vector_type(4))) float f32x4;

// ---- workspace layout (bytes) ----
#define OFF_COUNTS 0              // 8 int
#define OFF_SEL    128            // 4096 int   (e0 | e1<<8)
#define OFF_G0     16512          // 4096 float
#define OFF_TOK    32896          // 8*4096 int
#define OFF_GATE   295040         // 8*4096 float
#define OFF_LOADV  426112         // 4096*8 float
#define OFF_XB     1048576        // 4096*1024 bf16 (8 MB)
#define OFF_W1T    9437184        // 8*2048*1024 bf16 (32 MB) [n][k]
#define OFF_W2T    42991616       // 8*1024*2048 bf16 (32 MB) [n][k]
#define OFF_H      76546048       // 8192*2048 bf16 (32 MB)

__device__ __forceinline__ unsigned short f2bf(float f) {
  union { float f; unsigned u; } a; a.f = f;
  return (unsigned short)((a.u + 0x7FFFu + ((a.u >> 16) & 1u)) >> 16);
}

// async global -> LDS, 16B/lane; LDS dst = wave-uniform base (+ lane*16 by HW)
__device__ __forceinline__ void async16(const void* g, void* l) {
  __builtin_amdgcn_global_load_lds(
      (const __attribute__((address_space(1))) unsigned int*)g,
      (__attribute__((address_space(3))) unsigned int*)l, 16, 0, 0);
}

// ---- both weights: fp32 [E][K][N] -> bf16 [E][N][K], 64x64 tiles, one launch ----
__global__ __launch_bounds__(256) void transpose_both_kernel(
    const float* __restrict__ w1, unsigned short* __restrict__ w1t,
    const float* __restrict__ w2, unsigned short* __restrict__ w2t) {
  const int bx = blockIdx.x;
  const float* in; unsigned short* out;
  int K, N, kb, nb, e;
  if (bx < 4096) {               // w1: K=1024, N=2048 -> 16 x 32 tiles/expert
    K = D_MODEL; N = D_FF;
    e = bx >> 9; const int rem = bx & 511;
    nb = (rem & 31) * 64; kb = (rem >> 5) * 64;
    in = w1; out = w1t;
  } else {                       // w2: K=2048, N=1024 -> 32 x 16 tiles/expert
    K = D_FF; N = D_MODEL;
    const int b2x = bx - 4096;
    e = b2x >> 9; const int rem = b2x & 511;
    nb = (rem & 15) * 64; kb = (rem >> 4) * 64;
    in = w2; out = w2t;
  }
  __shared__ float tile[64][65];
  const int tid = threadIdx.x;
  const float* ine = in + (size_t)e * K * N;
  unsigned short* oute = out + (size_t)e * K * N;
  {
    const int c4 = tid & 15, rr = tid >> 4;
#pragma unroll
    for (int i = 0; i < 4; ++i) {
      const int row = i * 16 + rr;
      const float4 v = *(const float4*)(ine + (size_t)(kb + row) * N + nb + c4 * 4);
      tile[row][c4 * 4 + 0] = v.x;
      tile[row][c4 * 4 + 1] = v.y;
      tile[row][c4 * 4 + 2] = v.z;
      tile[row][c4 * 4 + 3] = v.w;
    }
  }
  __syncthreads();
  {
    const int n = tid >> 2, seg = tid & 3;
    unsigned short v[16];
#pragma unroll
    for (int j = 0; j < 16; ++j) v[j] = f2bf(tile[seg * 16 + j][n]);
    uint4* dst = (uint4*)(oute + (size_t)(nb + n) * K + kb + seg * 16);
    dst[0] = *(uint4*)&v[0];
    dst[1] = *(uint4*)&v[8];
  }
}

// ---- noisy top-k gating + fused x->bf16 conversion; zeroes counts ----
__global__ __launch_bounds__(256) void gating_kernel(
    const float* __restrict__ x, const float* __restrict__ noise,
    const float* __restrict__ wg, const float* __restrict__ wn,
    int* __restrict__ sel, float* __restrict__ g0out,
    float* __restrict__ loadvec, unsigned short* __restrict__ xb,
    int* __restrict__ counts) {
  if (blockIdx.x == 0 && threadIdx.x < N_EXP) counts[threadIdx.x] = 0;
  const int wave = threadIdx.x >> 6, lane = threadIdx.x & 63;
  const int t = blockIdx.x * 4 + wave;
  float ag[8], an[8];
#pragma unroll
  for (int e = 0; e < 8; ++e) { ag[e] = 0.f; an[e] = 0.f; }
  const float* xrow = x + (size_t)t * D_MODEL;
  for (int d = lane; d < D_MODEL; d += 64) {
    const float xv = xrow[d];
    const float4 wa = ((const float4*)(wg + (size_t)d * 8))[0];
    const float4 wb = ((const float4*)(wg + (size_t)d * 8))[1];
    const float4 na = ((const float4*)(wn + (size_t)d * 8))[0];
    const float4 nb = ((const float4*)(wn + (size_t)d * 8))[1];
    ag[0] += xv * wa.x; ag[1] += xv * wa.y; ag[2] += xv * wa.z; ag[3] += xv * wa.w;
    ag[4] += xv * wb.x; ag[5] += xv * wb.y; ag[6] += xv * wb.z; ag[7] += xv * wb.w;
    an[0] += xv * na.x; an[1] += xv * na.y; an[2] += xv * na.z; an[3] += xv * na.w;
    an[4] += xv * nb.x; an[5] += xv * nb.y; an[6] += xv * nb.z; an[7] += xv * nb.w;
  }
  {
    const float4* xv4 = (const float4*)xrow;
    ushort4* xb4 = (ushort4*)(xb + (size_t)t * D_MODEL);
#pragma unroll
    for (int i = 0; i < 4; ++i) {
      const float4 v = xv4[lane + i * 64];
      ushort4 o;
      o.x = f2bf(v.x); o.y = f2bf(v.y); o.z = f2bf(v.z); o.w = f2bf(v.w);
      xb4[lane + i * 64] = o;
    }
  }
#pragma unroll
  for (int e = 0; e < 8; ++e) {
#pragma unroll
    for (int off = 32; off > 0; off >>= 1) {
      ag[e] += __shfl_xor(ag[e], off, 64);
      an[e] += __shfl_xor(an[e], off, 64);
    }
  }
  float clean[8], sd[8], nz[8];
#pragma unroll
  for (int e = 0; e < 8; ++e) {
    clean[e] = ag[e];
    float s = an[e];
    s = (s > 20.f) ? s : log1pf(expf(s));
    sd[e] = s + 0.01f;
    nz[e] = clean[e] + noise[t * 8 + e] * sd[e];
  }
  float v0 = -1e30f, v1 = -1e30f, v2 = -1e30f; int i0 = 0, i1 = 0;
#pragma unroll
  for (int e = 0; e < 8; ++e) {
    const float v = nz[e];
    if (v > v0)      { v2 = v1; v1 = v0; i1 = i0; v0 = v; i0 = e; }
    else if (v > v1) { v2 = v1; v1 = v; i1 = e; }
    else if (v > v2) { v2 = v; }
  }
  const float ex = expf(v1 - v0);
  const float g0 = 1.f / (1.f + ex);
  if (lane == 0) { sel[t] = i0 | (i1 << 8); g0out[t] = g0; }
  if (lane < 8) {
    const int e = lane;
    const bool is_in = nz[e] > v2;
    const float thr = is_in ? v2 : v1;
    const float z = (clean[e] - thr) / sd[e];
    loadvec[t * 8 + e] = 0.5f * erfcf(-z * 0.70710678118654752f);
  }
}

// ---- per-expert token lists; 8 global atomics per block ----
__global__ __launch_bounds__(256) void build_lists_kernel(
    const int* __restrict__ sel, const float* __restrict__ g0a,
    int* __restrict__ counts, int* __restrict__ tok_list,
    float* __restrict__ gate_list) {
  __shared__ int hist[8], bbase[8];
  if (threadIdx.x < 8) hist[threadIdx.x] = 0;
  __syncthreads();
  const int t = blockIdx.x * 256 + threadIdx.x;
  const int s = sel[t];
  const int e0 = s & 255, e1 = (s >> 8) & 255;
  atomicAdd(&hist[e0], 1);
  atomicAdd(&hist[e1], 1);
  __syncthreads();
  if (threadIdx.x < 8) {
    bbase[threadIdx.x] = atomicAdd(&counts[threadIdx.x], hist[threadIdx.x]);
    hist[threadIdx.x] = 0;
  }
  __syncthreads();
  const float g = g0a[t];
  const int p0 = atomicAdd(&hist[e0], 1);
  const int idx0 = e0 * N_TOK + bbase[e0] + p0;
  tok_list[idx0] = t; gate_list[idx0] = g;
  const int p1 = atomicAdd(&hist[e1], 1);
  const int idx1 = e1 * N_TOK + bbase[e1] + p1;
  tok_list[idx1] = t; gate_list[idx1] = 1.f - g;
}

// ---- GEMM1: h = relu(gather(x) @ w1[e] + b1[e]); XOR-swizzled LDS ----
__global__ __launch_bounds__(256) void gemm1_kernel(
    const unsigned short* __restrict__ xb, const unsigned short* __restrict__ w1t,
    const float* __restrict__ b1,
    const int* __restrict__ counts,
    const int* __restrict__ tok_list, unsigned short* __restrict__ h) {
  const int e = blockIdx.x, nt = blockIdx.y, mt = blockIdx.z;
  const int cnt = counts[e];
  const int m0 = mt * 128;
  if (m0 >= cnt) return;
  int bs = 0;
#pragma unroll
  for (int i = 0; i < 8; ++i) bs += (i < e) ? counts[i] : 0;
  const int n0 = nt * 128;

  __shared__ __align__(16) unsigned short As[128 * 64];
  __shared__ __align__(16) unsigned short Bs[128 * 64];

  const int tid = threadIdx.x;
  const int wave = tid >> 6, lane = tid & 63;
  const int lrow = lane >> 3;
  const int scg  = (lane & 7) ^ lrow;

  const unsigned short* ap[4];
  const unsigned short* bp[4];
  unsigned short* adst[4];
  unsigned short* bdst[4];
#pragma unroll
  for (int c = 0; c < 4; ++c) {
    const int rr = wave * 32 + c * 8;
    const int arow = min(m0 + rr + lrow, cnt - 1);
    const int tok = tok_list[e * N_TOK + arow];
    ap[c] = xb + (size_t)tok * D_MODEL + scg * 8;
    bp[c] = w1t + (size_t)e * D_MODEL * D_FF + (size_t)(n0 + rr + lrow) * D_MODEL + scg * 8;
    adst[c] = As + rr * 64;
    bdst[c] = Bs + rr * 64;
  }

  const int wm = wave & 1, wn = wave >> 1;
  const int q = lane >> 4, r = lane & 15;
  const int r7 = r & 7;

  f32x4 acc[4][4];
#pragma unroll
  for (int a = 0; a < 4; ++a)
#pragma unroll
    for (int b = 0; b < 4; ++b) acc[a][b] = (f32x4){0.f, 0.f, 0.f, 0.f};

  for (int k0 = 0; k0 < D_MODEL; k0 += 64) {
#pragma unroll
    for (int c = 0; c < 4; ++c) {
      async16(ap[c], adst[c]);
      async16(bp[c], bdst[c]);
      ap[c] += 64; bp[c] += 64;
    }
    __syncthreads();
#pragma unroll
    for (int kk = 0; kk < 64; kk += 32) {
      const int gsw = (((kk >> 3) + q) ^ r7) * 8;
      short8 af[4], bfg[4];
#pragma unroll
      for (int t = 0; t < 4; ++t)
        af[t] = *(const short8*)(As + (wm * 64 + t * 16 + r) * 64 + gsw);
#pragma unroll
      for (int t = 0; t < 4; ++t)
        bfg[t] = *(const short8*)(Bs + (wn * 64 + t * 16 + r) * 64 + gsw);
#pragma unroll
      for (int tm = 0; tm < 4; ++tm)
#pragma unroll
        for (int tn = 0; tn < 4; ++tn)
          acc[tm][tn] = __builtin_amdgcn_mfma_f32_16x16x32_bf16(af[tm], bfg[tn], acc[tm][tn], 0, 0, 0);
    }
    __syncthreads();
  }

  float bv[4];
#pragma unroll
  for (int tn = 0; tn < 4; ++tn) bv[tn] = b1[e * D_FF + n0 + wn * 64 + tn * 16 + r];
#pragma unroll
  for (int tm = 0; tm < 4; ++tm) {
#pragma unroll
    for (int v = 0; v < 4; ++v) {
      const int i = wm * 64 + tm * 16 + q * 4 + v;
      if (m0 + i < cnt) {
        unsigned short* hrow = h + (size_t)(bs + m0 + i) * D_FF + n0 + wn * 64 + r;
#pragma unroll
        for (int tn = 0; tn < 4; ++tn)
          hrow[tn * 16] = f2bf(fmaxf(acc[tm][tn][v] + bv[tn], 0.f));
      }
    }
  }
}

// ---- GEMM2 (K-split 2): atomically accumulate gate*(h @ w2[e] [+ b2]) into y ----
__global__ __launch_bounds__(256) void gemm2_kernel(
    const unsigned short* __restrict__ h, const unsigned short* __restrict__ w2t,
    const float* __restrict__ b2,
    const int* __restrict__ counts,
    const int* __restrict__ tok_list, const float* __restrict__ gate_list,
    float* __restrict__ y) {
  const int e = blockIdx.x, nt = blockIdx.y;
  const int mt = blockIdx.z >> 1, kh = blockIdx.z & 1;
  const int cnt = counts[e];
  const int m0 = mt * 128;
  if (m0 >= cnt) return;
  int bs = 0;
#pragma unroll
  for (int i = 0; i < 8; ++i) bs += (i < e) ? counts[i] : 0;
  const int n0 = nt * 128;
  const int kbase = kh * (D_FF / 2);

  __shared__ __align__(16) unsigned short As[128 * 64];
  __shared__ __align__(16) unsigned short Bs[128 * 64];

  const int tid = threadIdx.x;
  const int wave = tid >> 6, lane = tid & 63;
  const int lrow = lane >> 3;
  const int scg  = (lane & 7) ^ lrow;

  const unsigned short* ap[4];
  const unsigned short* bp[4];
  unsigned short* adst[4];
  unsigned short* bdst[4];
#pragma unroll
  for (int c = 0; c < 4; ++c) {
    const int rr = wave * 32 + c * 8;
    const int arow = min(m0 + rr + lrow, cnt - 1);
    ap[c] = h + (size_t)(bs + arow) * D_FF + kbase + scg * 8;
    bp[c] = w2t + (size_t)e * D_MODEL * D_FF + (size_t)(n0 + rr + lrow) * D_FF + kbase + scg * 8;
    adst[c] = As + rr * 64;
    bdst[c] = Bs + rr * 64;
  }

  const int wm = wave & 1, wn = wave >> 1;
  const int q = lane >> 4, r = lane & 15;
  const int r7 = r & 7;

  f32x4 acc[4][4];
#pragma unroll
  for (int a = 0; a < 4; ++a)
#pragma unroll
    for (int b = 0; b < 4; ++b) acc[a][b] = (f32x4){0.f, 0.f, 0.f, 0.f};

  for (int k0 = 0; k0 < D_FF / 2; k0 += 64) {
#pragma unroll
    for (int c = 0; c < 4; ++c) {
      async16(ap[c], adst[c]);
      async16(bp[c], bdst[c]);
      ap[c] += 64; bp[c] += 64;
    }
    __syncthreads();
#pragma unroll
    for (int kk = 0; kk < 64; kk += 32) {
      const int gsw = (((kk >> 3) + q) ^ r7) * 8;
      short8 af[4], bfg[4];
#pragma unroll
      for (int t = 0; t < 4; ++t)
        af[t] = *(const short8*)(As + (wm * 64 + t * 16 + r) * 64 + gsw);
#pragma unroll
      for (int t = 0; t < 4; ++t)
        bfg[t] = *(const short8*)(Bs + (wn * 64 + t * 16 + r) * 64 + gsw);
#pragma unroll
      for (int tm = 0; tm < 4; ++tm)
#pragma unroll
        for (int tn = 0; tn < 4; ++tn)
          acc[tm][tn] = __builtin_amdgcn_mfma_f32_16x16x32_bf16(af[tm], bfg[tn], acc[tm][tn], 0, 0, 0);
    }
    __syncthreads();
  }

  float bv[4];
#pragma unroll
  for (int tn = 0; tn < 4; ++tn)
    bv[tn] = (kh == 0) ? b2[e * D_MODEL + n0 + wn * 64 + tn * 16 + r] : 0.f;
#pragma unroll
  for (int tm = 0; tm < 4; ++tm) {
#pragma unroll
    for (int v = 0; v < 4; ++v) {
      const int i = wm * 64 + tm * 16 + q * 4 + v;
      const int mrow = m0 + i;
      if (mrow < cnt) {
        const int idx = e * N_TOK + mrow;
        const int tok = tok_list[idx];
        const float g = gate_list[idx];
        float* orow = y + (size_t)tok * D_MODEL + n0 + wn * 64 + r;
#pragma unroll
        for (int tn = 0; tn < 4; ++tn)
          atomicAdd(&orow[tn * 16], (acc[tm][tn][v] + bv[tn]) * g);
      }
    }
  }
}

// ---- eps fixup over y; block 0 also computes loss into y[4M] ----
__global__ __launch_bounds__(256) void fixup_loss_kernel(
    float* __restrict__ y,
    const int* __restrict__ sel, const float* __restrict__ g0a,
    const float* __restrict__ loadvec) {
  const int i = blockIdx.x * 256 + threadIdx.x;
  float4 o = ((const float4*)y)[i];
  const float eps = 2.2204460492503131e-16f;
  if (o.x == 0.f) o.x = eps;
  if (o.y == 0.f) o.y = eps;
  if (o.z == 0.f) o.z = eps;
  if (o.w == 0.f) o.w = eps;
  ((float4*)y)[i] = o;

  if (blockIdx.x == 0) {
    float limp[8], lld[8];
#pragma unroll
    for (int e = 0; e < 8; ++e) { limp[e] = 0.f; lld[e] = 0.f; }
    for (int t = threadIdx.x; t < N_TOK; t += 256) {
      const int s = sel[t];
      const float g = g0a[t];
      const int e0 = s & 255, e1 = (s >> 8) & 255;
#pragma unroll
      for (int e = 0; e < 8; ++e)
        limp[e] += (e0 == e ? g : 0.f) + (e1 == e ? (1.f - g) : 0.f);
#pragma unroll
      for (int e = 0; e < 8; ++e) lld[e] += loadvec[t * 8 + e];
    }
#pragma unroll
    for (int e = 0; e < 8; ++e) {
#pragma unroll
      for (int off = 32; off > 0; off >>= 1) {
        limp[e] += __shfl_xor(limp[e], off, 64);
        lld[e]  += __shfl_xor(lld[e],  off, 64);
      }
    }
    __shared__ float red[4][16];
    const int wave = threadIdx.x >> 6, lane = threadIdx.x & 63;
    if (lane == 0) {
#pragma unroll
      for (int e = 0; e < 8; ++e) { red[wave][e] = limp[e]; red[wave][8 + e] = lld[e]; }
    }
    __syncthreads();
    if (threadIdx.x == 0) {
      double imp[8], ld[8];
      for (int e = 0; e < 8; ++e) {
        imp[e] = (double)red[0][e] + red[1][e] + red[2][e] + red[3][e];
        ld[e]  = (double)red[0][8 + e] + red[1][8 + e] + red[2][8 + e] + red[3][8 + e];
      }
      double mi = 0, ml = 0;
      for (int e = 0; e < 8; ++e) { mi += imp[e]; ml += ld[e]; }
      mi /= 8.0; ml /= 8.0;
      double vi = 0, vl = 0;
      for (int e = 0; e < 8; ++e) { vi += (imp[e] - mi) * (imp[e] - mi); vl += (ld[e] - ml) * (ld[e] - ml); }
      vi /= 7.0; vl /= 7.0;
      y[(size_t)N_TOK * D_MODEL] =
          (float)(0.1 * (vi / (mi * mi + 1e-10) + vl / (ml * ml + 1e-10)));
    }
  }
}

extern "C" void kernel_launch(void* const* d_in, const int* in_sizes, int n_in,
                              void* d_out, int out_size, void* d_ws, size_t ws_size,
                              hipStream_t stream) {
  const float* x     = (const float*)d_in[0];
  const float* noise = (const float*)d_in[1];
  const float* wg    = (const float*)d_in[2];
  const float* wn    = (const float*)d_in[3];
  const float* w1    = (const float*)d_in[4];
  const float* b1    = (const float*)d_in[5];
  const float* w2    = (const float*)d_in[6];
  const float* b2    = (const float*)d_in[7];
  float* out = (float*)d_out;

  char* ws = (char*)d_ws;
  int*   counts    = (int*)(ws + OFF_COUNTS);
  int*   sel       = (int*)(ws + OFF_SEL);
  float* g0a       = (float*)(ws + OFF_G0);
  int*   tok_list  = (int*)(ws + OFF_TOK);
  float* gate_list = (float*)(ws + OFF_GATE);
  float* loadvec   = (float*)(ws + OFF_LOADV);
  unsigned short* xb  = (unsigned short*)(ws + OFF_XB);
  unsigned short* w1t = (unsigned short*)(ws + OFF_W1T);
  unsigned short* w2t = (unsigned short*)(ws + OFF_W2T);
  unsigned short* h   = (unsigned short*)(ws + OFF_H);

  // zero the y region of out (gemm2 accumulates into it atomically)
  hipMemsetAsync(out, 0, (size_t)N_TOK * D_MODEL * sizeof(float), stream);

  gating_kernel<<<N_TOK / 4, 256, 0, stream>>>(x, noise, wg, wn, sel, g0a, loadvec, xb, counts);
  transpose_both_kernel<<<8192, 256, 0, stream>>>(w1, w1t, w2, w2t);
  build_lists_kernel<<<N_TOK / 256, 256, 0, stream>>>(sel, g0a, counts, tok_list, gate_list);
  gemm1_kernel<<<dim3(N_EXP, D_FF / 128, N_TOK / 128), 256, 0, stream>>>(
      xb, w1t, b1, counts, tok_list, h);
  gemm2_kernel<<<dim3(N_EXP, D_MODEL / 128, (N_TOK / 128) * 2), 256, 0, stream>>>(
      h, w2t, b2, counts, tok_list, gate_list, out);
  fixup_loss_kernel<<<(N_TOK * D_MODEL / 4) / 256, 256, 0, stream>>>(out, sel, g0a, loadvec);
}